// Round 10
// baseline (6749.324 us; speedup 1.0000x reference)
//
#include <hip/hip_runtime.h>
#include <hip/hip_bf16.h>

#define TSEQ  512
#define BATCH 64
#define HIDN  512
#define EMBD  100
#define NWG   64

typedef __attribute__((ext_vector_type(8))) short short8;
typedef __attribute__((ext_vector_type(4))) float f32x4;
typedef unsigned int u32;
typedef __attribute__((ext_vector_type(4))) u32 u32x4;
typedef __attribute__((ext_vector_type(2))) u32 u32x2;

// ---- workspace layout (bytes) ----
#define A_OFF   0ull                 // 512*64*512 bf16 = 33,554,432
#define HD_OFF  33554432ull          // post-BN hd: 512*64*512 bf16 = 33,554,432
#define HB_OFF  67108864ull          // granules: 2*64row*128g*16B = 262,144
#define FLG_OFF 67371008ull          // 64 flags * 64B pad = 4,096
#define KEY_OFF 67375104ull          // 6400 * 4 = 25,600
#define DW_OFF  67400704ull          // 112*512*2 = 114,688
#define ZERO_SPAN 291840ull          // HB + FLG + KEY

static __device__ __forceinline__ unsigned short f2bfbits(float f) {
    u32 u = __float_as_uint(f);
    u32 r = (u + 0x7fffu + ((u >> 16) & 1u)) >> 16;   // round-to-nearest-even
    return (unsigned short)r;
}
static __device__ __forceinline__ float sigf(float x) {
    return __builtin_amdgcn_rcpf(1.0f + __expf(-x));
}
static __device__ __forceinline__ float tanhfast(float x) {
    float t = __expf(-2.0f * fabsf(x));               // in (0,1], no overflow
    float r = (1.0f - t) * __builtin_amdgcn_rcpf(1.0f + t);
    return copysignf(r, x);
}

// ---------------- K1: dec_w -> bf16 (padded to 112 rows with zeros) ----------
__global__ void k_dw(const float* __restrict__ dw, unsigned short* __restrict__ dwb) {
    int i = blockIdx.x * 256 + threadIdx.x;            // 57,344 = 112*512
    float v = (i < EMBD * HIDN) ? dw[i] : 0.0f;
    dwb[i] = f2bfbits(v);
}

// ---------------- K2: embedding gather -> bf16 A[t][b][k] --------------------
__global__ void k_embed(const int* __restrict__ x, const float* __restrict__ emb,
                        unsigned short* __restrict__ A) {
    int g = blockIdx.x * 256 + threadIdx.x;            // 2,097,152 = T*B*64
    int k8 = g & 63;
    int bt = g >> 6;                                   // t*64 + b
    int b  = bt & 63;
    int t  = bt >> 6;
    int row = x[b * TSEQ + t];
    const float4* src = reinterpret_cast<const float4*>(emb + (size_t)row * HIDN + k8 * 8);
    float4 v0 = src[0], v1 = src[1];
    short8 s;
    s[0] = (short)f2bfbits(v0.x); s[1] = (short)f2bfbits(v0.y);
    s[2] = (short)f2bfbits(v0.z); s[3] = (short)f2bfbits(v0.w);
    s[4] = (short)f2bfbits(v1.x); s[5] = (short)f2bfbits(v1.y);
    s[6] = (short)f2bfbits(v1.z); s[7] = (short)f2bfbits(v1.w);
    *reinterpret_cast<short8*>(A + (size_t)g * 8) = s;
}

// ---------------- K3: persistent LSTM+BN+dropout ----------------------------
// ROUND-3 TOPOLOGY (proven 2055us): 64 flat WGs, WG wg owns h-cols wg*8..+8.
// Wave w: mb=w&3 (16-row M block), kh=w>>2 (0: x/A half, 1: h half).
// Weights bfr[16][2] in registers (128 VGPR-equiv, r3-proven shape).
// EXCHANGE = r8-proven tagged granules as PRIMARY, all-sc1:
//   writer wave0: 2x dwordx4 sc1 {2cols,tag,2cols,tag} per lane (row=lane).
//   ALL 8 waves cooperatively issue 16 granule loads each (64 VGPR transient,
//   no spill -- r4/r6 lesson) right after [A]; BN fills the flight; vmcnt(0);
//   tag check; <=4 bounded retries; fallback = r3-proven ack'd-flag poll +
//   reload (sc1 flag => sc1 data visible; writer flags unconditionally =>
//   liveness, r5 lesson). Granules strip to h_lds; waves 0-3 A-MFMA and
//   waves 4-7 h-MFMA run concurrently after [C].
__launch_bounds__(512)
__global__ void k_lstm(const float* __restrict__ wih, const float* __restrict__ whh,
                       const float* __restrict__ bih, const float* __restrict__ bhh,
                       const float* __restrict__ gamma, const float* __restrict__ beta,
                       const float* __restrict__ mask,
                       const unsigned short* __restrict__ A,
                       u32* __restrict__ hx,
                       unsigned short* __restrict__ hd,
                       u32* __restrict__ flg) {
    const int tid  = threadIdx.x;
    const int wg   = blockIdx.x;
    const int lane = tid & 63;
    const int w    = tid >> 6;        // wave 0..7
    const int mb   = w & 3;
    const int kh   = w >> 2;

    __shared__ float gbuf[2][64][33];                       // partial gates (kh halves)
    __shared__ __align__(16) unsigned short hstage[64][8];
    __shared__ __align__(16) unsigned short hdstage[2][64][8];
    __shared__ __align__(16) unsigned short h_lds[64][520]; // h(s+1) broadcast

    const int l15 = lane & 15;
    const int lk8 = (lane >> 4) * 8;

    // ---- load static B fragments into registers (once, r3 exact) ----
    const float* wsrc = kh ? whh : wih;
    short8 bfr[16][2];
    #pragma unroll
    for (int kk = 0; kk < 16; ++kk) {
        #pragma unroll
        for (int nb = 0; nb < 2; ++nb) {
            int nl   = nb * 16 + l15;                 // local gate col 0..31
            int gate = nl >> 3, jl = nl & 7;
            int ng   = gate * HIDN + wg * 8 + jl;     // row of w_ih/w_hh [4H, H]
            int kl   = kk * 32 + lk8;                 // 0..511 within this K half
            const float* p = wsrc + (size_t)ng * HIDN + kl;
            short8 bb;
            #pragma unroll
            for (int e = 0; e < 8; ++e) bb[e] = (short)f2bfbits(p[e]);
            bfr[kk][nb] = bb;
        }
    }

    // ---- pointwise-role constants (r3 exact) ----
    const int jj = wg * 8 + w;
    const float bias_i = bih[jj]          + bhh[jj];
    const float bias_f = bih[512 + jj]    + bhh[512 + jj];
    const float bias_g = bih[1024 + jj]   + bhh[1024 + jj];
    const float bias_o = bih[1536 + jj]   + bhh[1536 + jj];
    const float gam = gamma[jj], bet = beta[jj];
    const float mk  = mask[(size_t)lane * HIDN + jj] * (1.0f / 0.7f);
    float c = 0.0f;

    const int arow = mb * 16 + l15;   // M row for MFMA A-fragment loads
    const u32* fpoll = flg + lane * 16;

    // ---- prologue: gbuf[1] = 0; gbuf[0] = A(0) @ Wih^T (r3 exact) ----
    {
        float* g1 = &gbuf[1][0][0];
        for (int i = tid; i < 64 * 33; i += 512) g1[i] = 0.0f;
    }
    __syncthreads();
    if (kh == 0) {
        const unsigned short* abase = A + (size_t)arow * HIDN;
        f32x4 a0 = {0.f,0.f,0.f,0.f}, a1 = {0.f,0.f,0.f,0.f};
        #pragma unroll
        for (int kk = 0; kk < 16; ++kk) {
            short8 a = *reinterpret_cast<const short8*>(abase + kk * 32 + lk8);
            a0 = __builtin_amdgcn_mfma_f32_16x16x32_bf16(a, bfr[kk][0], a0, 0, 0, 0);
            a1 = __builtin_amdgcn_mfma_f32_16x16x32_bf16(a, bfr[kk][1], a1, 0, 0, 0);
        }
        #pragma unroll
        for (int r = 0; r < 4; ++r) {
            int row = mb * 16 + (lane >> 4) * 4 + r;
            gbuf[0][row][l15]      = a0[r];
            gbuf[0][row][16 + l15] = a1[r];
        }
    }
    __syncthreads();

    for (int s = 0; s < TSEQ; ++s) {
        // ---- pointwise: gates(s) -> c, h(s+1) (r3 exact) ----
        float gi = gbuf[0][lane][w]      + gbuf[1][lane][w]      + bias_i;
        float gf = gbuf[0][lane][8 + w]  + gbuf[1][lane][8 + w]  + bias_f;
        float gg = gbuf[0][lane][16 + w] + gbuf[1][lane][16 + w] + bias_g;
        float go = gbuf[0][lane][24 + w] + gbuf[1][lane][24 + w] + bias_o;
        float iv = sigf(gi), fv = sigf(gf), gv = tanhfast(gg), ov = sigf(go);
        c = fv * c + iv * gv;
        float h = ov * tanhfast(c);
        hstage[lane][w] = f2bfbits(h);
        __syncthreads();                                        // [A]

        const int last = (s == TSEQ - 1);
        const int sb   = (s + 1) & 1;
        const u32 tgt  = (u32)(s + 1);

        u32x4 gq[16];
        const u32* gp = hx + ((size_t)sb * 64 + lane) * 512 + w * 64;

        if (!last) {
            // ---- wave0: publish h(s+1) granules sc1 (fire-and-forget) ----
            if (w == 0) {
                const u32* hrow = reinterpret_cast<const u32*>(&hstage[lane][0]);
                u32 d0 = hrow[0], d1 = hrow[1], d2 = hrow[2], d3 = hrow[3];
                u32x4 q0 = {d0, tgt, d1, tgt};
                u32x4 q1 = {d2, tgt, d3, tgt};
                u32* dst = hx + ((size_t)sb * 64 + lane) * 512 + wg * 8;
                asm volatile("global_store_dwordx4 %0, %1, off sc1" :: "v"(dst), "v"(q0) : "memory");
                asm volatile("global_store_dwordx4 %0, %1, off sc1" :: "v"(dst + 4), "v"(q1) : "memory");
            }
            // ---- all waves: issue this wave's 16 granule loads ----
            #pragma unroll
            for (int i = 0; i < 16; ++i) {
                asm volatile("global_load_dwordx4 %0, %1, off sc1"
                             : "=v"(gq[i]) : "v"(gp + i * 4) : "memory");
            }
        }

        // ---- BatchNorm + locked dropout (fills the load-flight window) ----
        {
            float s1 = h, s2 = h * h;
            #pragma unroll
            for (int m = 1; m < 64; m <<= 1) {
                s1 += __shfl_xor(s1, m, 64);
                s2 += __shfl_xor(s2, m, 64);
            }
            float mu  = s1 * (1.0f / 64.0f);
            float var = s2 * (1.0f / 64.0f) - mu * mu;
            float hn  = (h - mu) * rsqrtf(var + 1e-5f) * gam + bet;
            hdstage[s & 1][lane][w] = f2bfbits(hn * mk);
        }

        if (!last) {
            asm volatile("s_waitcnt vmcnt(0)" ::: "memory");    // stores ack'd too
            __builtin_amdgcn_sched_barrier(0);
            // ---- wave0 lane0: flag AFTER granule-store ack (fallback order) ----
            if (w == 0 && lane == 0) {
                const u32* myf = flg + wg * 16;
                asm volatile("global_store_dword %0, %1, off sc1" :: "v"(myf), "v"(tgt) : "memory");
            }
            // ---- tag check + <=4 bounded retries ----
            int ok;
            {
                int o = 1;
                #pragma unroll
                for (int i = 0; i < 16; ++i) o &= (gq[i].y == tgt) & (gq[i].w == tgt);
                ok = __all(o);
            }
            #pragma unroll 1
            for (int att = 0; att < 4 && !ok; ++att) {
                #pragma unroll
                for (int i = 0; i < 16; ++i) {
                    if ((gq[i].y != tgt) | (gq[i].w != tgt))
                        asm volatile("global_load_dwordx4 %0, %1, off sc1"
                                     : "=v"(gq[i]) : "v"(gp + i * 4) : "memory");
                }
                asm volatile("s_waitcnt vmcnt(0)" ::: "memory");
                __builtin_amdgcn_sched_barrier(0);
                int o = 1;
                #pragma unroll
                for (int i = 0; i < 16; ++i) o &= (gq[i].y == tgt) & (gq[i].w == tgt);
                ok = __all(o);
            }
            if (!ok) {
                // fallback: proven flag poll (liveness), then reload all
                u32 v;
                do {
                    asm volatile("global_load_dword %0, %1, off sc1"
                                 : "=v"(v) : "v"(fpoll) : "memory");
                    asm volatile("s_waitcnt vmcnt(0)" ::: "memory");
                } while (!__all((int)(v >= tgt)));
                __builtin_amdgcn_sched_barrier(0);
                #pragma unroll
                for (int i = 0; i < 16; ++i)
                    asm volatile("global_load_dwordx4 %0, %1, off sc1"
                                 : "=v"(gq[i]) : "v"(gp + i * 4) : "memory");
                asm volatile("s_waitcnt vmcnt(0)" ::: "memory");
                __builtin_amdgcn_sched_barrier(0);
            }
            // ---- strip tags -> h_lds broadcast (4 cols per 8B store) ----
            #pragma unroll
            for (int i = 0; i < 16; ++i) {
                u32x2 d = {gq[i].x, gq[i].z};
                *reinterpret_cast<u32x2*>(&h_lds[lane][(w * 16 + i) * 4]) = d;
            }
        }
        __syncthreads();                                        // [C]

        if (!last) {
            if (kh == 0) {
                // ---- A-half MFMA for gates(s+1) (r3 exact) ----
                const unsigned short* abase = A + ((size_t)(s + 1) * 64 + arow) * HIDN;
                f32x4 a0 = {0.f,0.f,0.f,0.f}, a1 = {0.f,0.f,0.f,0.f};
                #pragma unroll
                for (int kk = 0; kk < 16; ++kk) {
                    short8 a = *reinterpret_cast<const short8*>(abase + kk * 32 + lk8);
                    a0 = __builtin_amdgcn_mfma_f32_16x16x32_bf16(a, bfr[kk][0], a0, 0, 0, 0);
                    a1 = __builtin_amdgcn_mfma_f32_16x16x32_bf16(a, bfr[kk][1], a1, 0, 0, 0);
                }
                #pragma unroll
                for (int r = 0; r < 4; ++r) {
                    int row = mb * 16 + (lane >> 4) * 4 + r;
                    gbuf[0][row][l15]      = a0[r];
                    gbuf[0][row][16 + l15] = a1[r];
                }
            } else {
                // ---- h-half MFMA from h_lds ----
                f32x4 a0 = {0.f,0.f,0.f,0.f}, a1 = {0.f,0.f,0.f,0.f};
                #pragma unroll
                for (int kk = 0; kk < 16; ++kk) {
                    short8 a = *reinterpret_cast<const short8*>(&h_lds[arow][kk * 32 + lk8]);
                    a0 = __builtin_amdgcn_mfma_f32_16x16x32_bf16(a, bfr[kk][0], a0, 0, 0, 0);
                    a1 = __builtin_amdgcn_mfma_f32_16x16x32_bf16(a, bfr[kk][1], a1, 0, 0, 0);
                }
                #pragma unroll
                for (int r = 0; r < 4; ++r) {
                    int row = mb * 16 + (lane >> 4) * 4 + r;
                    gbuf[1][row][l15]      = a0[r];
                    gbuf[1][row][16 + l15] = a1[r];
                }
            }
        }
        __syncthreads();                                        // [B]

        // ---- wave1 drains hd(s) (r3 exact) ----
        if (w == 1) {
            short8 dv = *reinterpret_cast<const short8*>(&hdstage[s & 1][lane][0]);
            *reinterpret_cast<short8*>(hd + ((size_t)s * 64 + lane) * HIDN + wg * 8) = dv;
        }
    }
}

// ---------------- K4: decode GEMM + running max (one WG per t, r3 exact) -----
__launch_bounds__(256)
__global__ void k_decode(const unsigned short* __restrict__ hd,
                         const unsigned short* __restrict__ dwb,
                         u32* __restrict__ key) {
    const int t    = blockIdx.x;
    const int tid  = threadIdx.x;
    const int lane = tid & 63;
    const int w    = tid >> 6;
    const int l15  = lane & 15;
    const int lk8  = (lane >> 4) * 8;
    const int brow = w * 16 + l15;

    const unsigned short* abase = hd + ((size_t)t * 64 + brow) * HIDN;
    f32x4 acc[7];
    #pragma unroll
    for (int nb = 0; nb < 7; ++nb) acc[nb] = (f32x4){0.f, 0.f, 0.f, 0.f};

    #pragma unroll
    for (int kk = 0; kk < 16; ++kk) {
        short8 a = *reinterpret_cast<const short8*>(abase + kk * 32 + lk8);
        #pragma unroll
        for (int nb = 0; nb < 7; ++nb) {
            short8 b = *reinterpret_cast<const short8*>(
                dwb + (size_t)(nb * 16 + l15) * HIDN + kk * 32 + lk8);
            acc[nb] = __builtin_amdgcn_mfma_f32_16x16x32_bf16(a, b, acc[nb], 0, 0, 0);
        }
    }
    #pragma unroll
    for (int nb = 0; nb < 7; ++nb) {
        int n = nb * 16 + l15;
        if (n < EMBD) {
            #pragma unroll
            for (int r = 0; r < 4; ++r) {
                int b = w * 16 + (lane >> 4) * 4 + r;
                u32 u  = __float_as_uint(acc[nb][r]);
                u32 kv = (u & 0x80000000u) ? ~u : (u | 0x80000000u);  // order-preserving
                atomicMax(&key[b * EMBD + n], kv);
            }
        }
    }
}

// ---------------- K5: inverse transform + decoder bias -----------------------
__global__ void k_final(const u32* __restrict__ key, const float* __restrict__ db,
                        float* __restrict__ out) {
    int i = blockIdx.x * 256 + threadIdx.x;
    if (i < BATCH * EMBD) {
        u32 k = key[i];
        u32 u = (k & 0x80000000u) ? (k & 0x7fffffffu) : ~k;
        out[i] = __uint_as_float(u) + db[i % EMBD];
    }
}

extern "C" void kernel_launch(void* const* d_in, const int* in_sizes, int n_in,
                              void* d_out, int out_size, void* d_ws, size_t ws_size,
                              hipStream_t stream) {
    const int*   x   = (const int*)d_in[0];
    const float* emb = (const float*)d_in[1];
    const float* wih = (const float*)d_in[2];
    const float* whh = (const float*)d_in[3];
    const float* bih = (const float*)d_in[4];
    const float* bhh = (const float*)d_in[5];
    const float* gam = (const float*)d_in[6];
    const float* bet = (const float*)d_in[7];
    const float* dw  = (const float*)d_in[8];
    const float* db  = (const float*)d_in[9];
    const float* msk = (const float*)d_in[10];

    char* ws = (char*)d_ws;
    unsigned short* A   = (unsigned short*)(ws + A_OFF);
    unsigned short* hd  = (unsigned short*)(ws + HD_OFF);
    u32*            hx  = (u32*)(ws + HB_OFF);
    u32*            flg = (u32*)(ws + FLG_OFF);
    u32*            key = (u32*)(ws + KEY_OFF);
    unsigned short* dwb = (unsigned short*)(ws + DW_OFF);

    hipMemsetAsync(ws + HB_OFF, 0, ZERO_SPAN, stream);      // granules + flags + keys
    k_dw    <<<224,  256, 0, stream>>>(dw, dwb);
    k_embed <<<8192, 256, 0, stream>>>(x, emb, A);
    k_lstm  <<<NWG,  512, 0, stream>>>(wih, whh, bih, bhh, gam, bet, msk, A, hx, hd, flg);
    k_decode<<<TSEQ, 256, 0, stream>>>(hd, dwb, key);
    k_final <<<25,   256, 0, stream>>>(key, db, (float*)d_out);
}

// Round 11
// 3739.075 us; speedup vs baseline: 1.8051x; 1.8051x over previous
//
#include <hip/hip_runtime.h>
#include <hip/hip_bf16.h>

#define TSEQ  512
#define BATCH 64
#define HIDN  512
#define EMBD  100
#define NWG   64

typedef __attribute__((ext_vector_type(8))) short short8;
typedef __attribute__((ext_vector_type(4))) float f32x4;
typedef unsigned int u32;
typedef __attribute__((ext_vector_type(4))) u32 u32x4;

// ---- workspace layout (bytes) ----
#define A_OFF   0ull                 // 512*64*512 bf16 = 33,554,432
#define HD_OFF  33554432ull          // raw-ish h for BN/decode: 33,554,432
#define HB_OFF  67108864ull          // h exchange: 3 slots * 64*512 bf16 = 196,608
#define FLG_OFF 67305472ull          // 64 flags * 64B pad = 4,096
#define KEY_OFF 67309568ull          // 6400 * 4 = 25,600
#define DW_OFF  67335168ull          // 112*512*2 = 114,688
#define MS_SPAN 29696ull             // FLG + KEY (zeroed per call)

static __device__ __forceinline__ unsigned short f2bfbits(float f) {
    u32 u = __float_as_uint(f);
    u32 r = (u + 0x7fffu + ((u >> 16) & 1u)) >> 16;   // round-to-nearest-even
    return (unsigned short)r;
}
static __device__ __forceinline__ float bf2f(unsigned short b) {
    return __uint_as_float(((u32)b) << 16);
}
static __device__ __forceinline__ float sigf(float x) {
    return __builtin_amdgcn_rcpf(1.0f + __expf(-x));
}
static __device__ __forceinline__ float tanhfast(float x) {
    float t = __expf(-2.0f * fabsf(x));               // in (0,1], no overflow
    float r = (1.0f - t) * __builtin_amdgcn_rcpf(1.0f + t);
    return copysignf(r, x);
}

// ---------------- K1: dec_w -> bf16 (padded to 112 rows with zeros) ----------
__global__ void k_dw(const float* __restrict__ dw, unsigned short* __restrict__ dwb) {
    int i = blockIdx.x * 256 + threadIdx.x;            // 57,344 = 112*512
    float v = (i < EMBD * HIDN) ? dw[i] : 0.0f;
    dwb[i] = f2bfbits(v);
}

// ---------------- K1b: init h-exchange slots' parity bits --------------------
// slot j is first READ at step s where (s+1)%3==j expecting parity (s+1)&1:
// slot1@s=0 expects 1, slot2@s=1 expects 0, slot0@s=2 expects 1.
// Initialize each slot with the COMPLEMENT so stale-initial is rejected:
// slot0=0, slot1=0, slot2=1 (LSB of every u16).
__global__ void k_hxinit(unsigned short* __restrict__ hx) {
    int i = blockIdx.x * 256 + threadIdx.x;            // 98,304 = 3*64*512
    if (i < 3 * BATCH * HIDN) {
        int slot = i >> 15;                            // /32768
        hx[i] = (slot == 2) ? 1 : 0;
    }
}

// ---------------- K2: embedding gather -> bf16 A[t][b][k] --------------------
__global__ void k_embed(const int* __restrict__ x, const float* __restrict__ emb,
                        unsigned short* __restrict__ A) {
    int g = blockIdx.x * 256 + threadIdx.x;            // 2,097,152 = T*B*64
    int k8 = g & 63;
    int bt = g >> 6;                                   // t*64 + b
    int b  = bt & 63;
    int t  = bt >> 6;
    int row = x[b * TSEQ + t];
    const float4* src = reinterpret_cast<const float4*>(emb + (size_t)row * HIDN + k8 * 8);
    float4 v0 = src[0], v1 = src[1];
    short8 s;
    s[0] = (short)f2bfbits(v0.x); s[1] = (short)f2bfbits(v0.y);
    s[2] = (short)f2bfbits(v0.z); s[3] = (short)f2bfbits(v0.w);
    s[4] = (short)f2bfbits(v1.x); s[5] = (short)f2bfbits(v1.y);
    s[6] = (short)f2bfbits(v1.z); s[7] = (short)f2bfbits(v1.w);
    *reinterpret_cast<short8*>(A + (size_t)g * 8) = s;
}

// ---------------- K3: persistent LSTM+BN+dropout ----------------------------
// ROUND-3 TOPOLOGY EXACT (proven 2055us): 64 flat WGs, WG wg owns h-cols
// wg*8..+8; wave w: mb=w&3, kh=w>>2; weights bfr[16][2] in regs; kh=0 A-MFMA
// fully decoupled from the sync; only barriers [A],[B].
// EXCHANGE upgrade: SELF-VALIDATING h -- every bf16 h element has its LSB
// forced to parity (s+1)&1 by the writer. 3-slot rotation => stale content
// is one generation away (odd step distance) => OPPOSITE parity => rejected,
// at ANY store-tearing granularity (each 2B element self-tags). Readers do
// r3-identical 16x16B loads (detect+data in the SAME round trip), check
// parity on both 8B halves, <=6 bounded retries, then fall back to the
// r3-proven ack'd-flag poll + reload (guaranteed liveness; flag => fresh).
// Clean h (LSB intact) goes to hd for BN/decode; only the recurrence matmul
// sees the ~2^-8 LSB perturbation.
__launch_bounds__(512)
__global__ void k_lstm(const float* __restrict__ wih, const float* __restrict__ whh,
                       const float* __restrict__ bih, const float* __restrict__ bhh,
                       const float* __restrict__ gamma, const float* __restrict__ beta,
                       const float* __restrict__ mask,
                       const unsigned short* __restrict__ A,
                       unsigned short* __restrict__ hx,
                       unsigned short* __restrict__ hd,
                       u32* __restrict__ flg) {
    const int tid  = threadIdx.x;
    const int wg   = blockIdx.x;
    const int lane = tid & 63;
    const int w    = tid >> 6;        // wave 0..7
    const int mb   = w & 3;
    const int kh   = w >> 2;

    __shared__ float gbuf[2][64][33];                       // partial gates (kh halves)
    __shared__ __align__(16) unsigned short hstage[64][8];
    __shared__ __align__(16) unsigned short hdstage[2][64][8];

    const int l15 = lane & 15;
    const int lk8 = (lane >> 4) * 8;

    // ---- load static B fragments into registers (once, r3 exact) ----
    const float* wsrc = kh ? whh : wih;
    short8 bfr[16][2];
    #pragma unroll
    for (int kk = 0; kk < 16; ++kk) {
        #pragma unroll
        for (int nb = 0; nb < 2; ++nb) {
            int nl   = nb * 16 + l15;                 // local gate col 0..31
            int gate = nl >> 3, jl = nl & 7;
            int ng   = gate * HIDN + wg * 8 + jl;     // row of w_ih/w_hh [4H, H]
            int kl   = kk * 32 + lk8;                 // 0..511 within this K half
            const float* p = wsrc + (size_t)ng * HIDN + kl;
            short8 bb;
            #pragma unroll
            for (int e = 0; e < 8; ++e) bb[e] = (short)f2bfbits(p[e]);
            bfr[kk][nb] = bb;
        }
    }

    // ---- pointwise-role constants (r3 exact) ----
    const int jj = wg * 8 + w;
    const float bias_i = bih[jj]          + bhh[jj];
    const float bias_f = bih[512 + jj]    + bhh[512 + jj];
    const float bias_g = bih[1024 + jj]   + bhh[1024 + jj];
    const float bias_o = bih[1536 + jj]   + bhh[1536 + jj];
    const float gam = gamma[jj], bet = beta[jj];
    const float mk  = mask[(size_t)lane * HIDN + jj] * (1.0f / 0.7f);
    float c = 0.0f;

    const int arow = mb * 16 + l15;   // M row for MFMA A-fragment loads
    const u32* fpoll = flg + lane * 16;

    // ---- prologue: gbuf[1] = 0; gbuf[0] = A(0) @ Wih^T (r3 exact) ----
    {
        float* g1 = &gbuf[1][0][0];
        for (int i = tid; i < 64 * 33; i += 512) g1[i] = 0.0f;
    }
    __syncthreads();
    if (kh == 0) {
        const unsigned short* abase = A + (size_t)arow * HIDN;
        f32x4 a0 = {0.f,0.f,0.f,0.f}, a1 = {0.f,0.f,0.f,0.f};
        #pragma unroll
        for (int kk = 0; kk < 16; ++kk) {
            short8 a = *reinterpret_cast<const short8*>(abase + kk * 32 + lk8);
            a0 = __builtin_amdgcn_mfma_f32_16x16x32_bf16(a, bfr[kk][0], a0, 0, 0, 0);
            a1 = __builtin_amdgcn_mfma_f32_16x16x32_bf16(a, bfr[kk][1], a1, 0, 0, 0);
        }
        #pragma unroll
        for (int r = 0; r < 4; ++r) {
            int row = mb * 16 + (lane >> 4) * 4 + r;
            gbuf[0][row][l15]      = a0[r];
            gbuf[0][row][16 + l15] = a1[r];
        }
    }
    __syncthreads();

    int sl = 1;                       // slot for h(s+1) = (s+1)%3

    for (int s = 0; s < TSEQ; ++s) {
        // ---- pointwise: gates(s) -> c, h(s+1) (r3 exact) ----
        float gi = gbuf[0][lane][w]      + gbuf[1][lane][w]      + bias_i;
        float gf = gbuf[0][lane][8 + w]  + gbuf[1][lane][8 + w]  + bias_f;
        float gg = gbuf[0][lane][16 + w] + gbuf[1][lane][16 + w] + bias_g;
        float go = gbuf[0][lane][24 + w] + gbuf[1][lane][24 + w] + bias_o;
        float iv = sigf(gi), fv = sigf(gf), gv = tanhfast(gg), ov = sigf(go);
        c = fv * c + iv * gv;
        float h = ov * tanhfast(c);
        hstage[lane][w] = f2bfbits(h);
        __syncthreads();                                        // [A]

        const int last = (s == TSEQ - 1);
        const u32 tgt  = (u32)(s + 1);
        const u32 pm   = (tgt & 1u) ? 0x00010001u : 0u;         // parity mask

        u32x4 hf[16];
        const unsigned short* hbase = hx + (size_t)sl * 32768 + (size_t)arow * HIDN;

        if (!last) {
            // ---- wave0: publish h(s+1) with LSB=parity (fire-and-forget) ----
            if (w == 0) {
                const u32* hrow = reinterpret_cast<const u32*>(&hstage[lane][0]);
                u32x4 q;
                q.x = (hrow[0] & 0xFFFEFFFEu) | pm;
                q.y = (hrow[1] & 0xFFFEFFFEu) | pm;
                q.z = (hrow[2] & 0xFFFEFFFEu) | pm;
                q.w = (hrow[3] & 0xFFFEFFFEu) | pm;
                u32* dst = (u32*)(hx + (size_t)sl * 32768 + (size_t)lane * HIDN + wg * 8);
                asm volatile("global_store_dwordx4 %0, %1, off sc1" :: "v"(dst), "v"(q) : "memory");
            }
            // ---- kh=1 waves: speculative h loads (detect+data, same RT) ----
            if (kh == 1) {
                #pragma unroll
                for (int kk = 0; kk < 16; ++kk) {
                    const unsigned short* p = hbase + kk * 32 + lk8;
                    asm volatile("global_load_dwordx4 %0, %1, off sc1"
                                 : "=v"(hf[kk]) : "v"(p) : "memory");
                }
            }
        }

        // ---- BatchNorm + locked dropout (fills store/load flight) ----
        {
            float s1 = h, s2 = h * h;
            #pragma unroll
            for (int m = 1; m < 64; m <<= 1) {
                s1 += __shfl_xor(s1, m, 64);
                s2 += __shfl_xor(s2, m, 64);
            }
            float mu  = s1 * (1.0f / 64.0f);
            float var = s2 * (1.0f / 64.0f) - mu * mu;
            float hn  = (h - mu) * rsqrtf(var + 1e-5f) * gam + bet;
            hdstage[s & 1][lane][w] = f2bfbits(hn * mk);
        }

        if (!last) {
            if (w == 0) {
                // ---- ack granule store, then publish flag (fallback path) ----
                asm volatile("s_waitcnt vmcnt(0)" ::: "memory");
                if (lane == 0) {
                    const u32* myf = flg + wg * 16;
                    asm volatile("global_store_dword %0, %1, off sc1" :: "v"(myf), "v"(tgt) : "memory");
                }
            }
            if (kh == 0) {
                // ---- A-half MFMA for gates(s+1) (r3 exact, sync-free) ----
                const unsigned short* abase = A + ((size_t)(s + 1) * 64 + arow) * HIDN;
                f32x4 a0 = {0.f,0.f,0.f,0.f}, a1 = {0.f,0.f,0.f,0.f};
                #pragma unroll
                for (int kk = 0; kk < 16; ++kk) {
                    short8 a = *reinterpret_cast<const short8*>(abase + kk * 32 + lk8);
                    a0 = __builtin_amdgcn_mfma_f32_16x16x32_bf16(a, bfr[kk][0], a0, 0, 0, 0);
                    a1 = __builtin_amdgcn_mfma_f32_16x16x32_bf16(a, bfr[kk][1], a1, 0, 0, 0);
                }
                #pragma unroll
                for (int r = 0; r < 4; ++r) {
                    int row = mb * 16 + (lane >> 4) * 4 + r;
                    gbuf[0][row][l15]      = a0[r];
                    gbuf[0][row][16 + l15] = a1[r];
                }
            } else {
                // ---- validate parity (both 8B halves; 8B atomicity r8-proven) ----
                asm volatile("s_waitcnt vmcnt(0)" ::: "memory");
                __builtin_amdgcn_sched_barrier(0);
                int ok;
                {
                    int o = 1;
                    #pragma unroll
                    for (int kk = 0; kk < 16; ++kk)
                        o &= ((hf[kk].x & 0x00010001u) == pm)
                           & ((hf[kk].z & 0x00010001u) == pm);
                    ok = __all(o);
                }
                #pragma unroll 1
                for (int att = 0; att < 6 && !ok; ++att) {
                    #pragma unroll
                    for (int kk = 0; kk < 16; ++kk) {
                        const unsigned short* p = hbase + kk * 32 + lk8;
                        asm volatile("global_load_dwordx4 %0, %1, off sc1"
                                     : "=v"(hf[kk]) : "v"(p) : "memory");
                    }
                    asm volatile("s_waitcnt vmcnt(0)" ::: "memory");
                    __builtin_amdgcn_sched_barrier(0);
                    int o = 1;
                    #pragma unroll
                    for (int kk = 0; kk < 16; ++kk)
                        o &= ((hf[kk].x & 0x00010001u) == pm)
                           & ((hf[kk].z & 0x00010001u) == pm);
                    ok = __all(o);
                }
                if (!ok) {
                    // fallback: r3-proven flag poll (liveness), then reload
                    u32 v;
                    do {
                        asm volatile("global_load_dword %0, %1, off sc1"
                                     : "=v"(v) : "v"(fpoll) : "memory");
                        asm volatile("s_waitcnt vmcnt(0)" ::: "memory");
                    } while (!__all((int)(v >= tgt)));
                    __builtin_amdgcn_sched_barrier(0);
                    #pragma unroll
                    for (int kk = 0; kk < 16; ++kk) {
                        const unsigned short* p = hbase + kk * 32 + lk8;
                        asm volatile("global_load_dwordx4 %0, %1, off sc1"
                                     : "=v"(hf[kk]) : "v"(p) : "memory");
                    }
                    asm volatile("s_waitcnt vmcnt(0)" ::: "memory");
                    __builtin_amdgcn_sched_barrier(0);
                }
                // ---- h-half MFMA directly from registers (r3 exact shape) ----
                f32x4 a0 = {0.f,0.f,0.f,0.f}, a1 = {0.f,0.f,0.f,0.f};
                #pragma unroll
                for (int kk = 0; kk < 16; ++kk) {
                    short8 a = *reinterpret_cast<short8*>(&hf[kk]);
                    a0 = __builtin_amdgcn_mfma_f32_16x16x32_bf16(a, bfr[kk][0], a0, 0, 0, 0);
                    a1 = __builtin_amdgcn_mfma_f32_16x16x32_bf16(a, bfr[kk][1], a1, 0, 0, 0);
                }
                #pragma unroll
                for (int r = 0; r < 4; ++r) {
                    int row = mb * 16 + (lane >> 4) * 4 + r;
                    gbuf[1][row][l15]      = a0[r];
                    gbuf[1][row][16 + l15] = a1[r];
                }
            }
        }
        __syncthreads();                                        // [B]

        // ---- wave1 drains clean h(s)-derived hd (r3 exact) ----
        if (w == 1) {
            short8 dv = *reinterpret_cast<const short8*>(&hdstage[s & 1][lane][0]);
            *reinterpret_cast<short8*>(hd + ((size_t)s * 64 + lane) * HIDN + wg * 8) = dv;
        }

        sl = (sl == 2) ? 0 : sl + 1;                            // rotate slot
    }
}

// ---------------- K4: decode GEMM + running max (one WG per t, r3 exact) -----
__launch_bounds__(256)
__global__ void k_decode(const unsigned short* __restrict__ hd,
                         const unsigned short* __restrict__ dwb,
                         u32* __restrict__ key) {
    const int t    = blockIdx.x;
    const int tid  = threadIdx.x;
    const int lane = tid & 63;
    const int w    = tid >> 6;
    const int l15  = lane & 15;
    const int lk8  = (lane >> 4) * 8;
    const int brow = w * 16 + l15;

    const unsigned short* abase = hd + ((size_t)t * 64 + brow) * HIDN;
    f32x4 acc[7];
    #pragma unroll
    for (int nb = 0; nb < 7; ++nb) acc[nb] = (f32x4){0.f, 0.f, 0.f, 0.f};

    #pragma unroll
    for (int kk = 0; kk < 16; ++kk) {
        short8 a = *reinterpret_cast<const short8*>(abase + kk * 32 + lk8);
        #pragma unroll
        for (int nb = 0; nb < 7; ++nb) {
            short8 b = *reinterpret_cast<const short8*>(
                dwb + (size_t)(nb * 16 + l15) * HIDN + kk * 32 + lk8);
            acc[nb] = __builtin_amdgcn_mfma_f32_16x16x32_bf16(a, b, acc[nb], 0, 0, 0);
        }
    }
    #pragma unroll
    for (int nb = 0; nb < 7; ++nb) {
        int n = nb * 16 + l15;
        if (n < EMBD) {
            #pragma unroll
            for (int r = 0; r < 4; ++r) {
                int b = w * 16 + (lane >> 4) * 4 + r;
                u32 u  = __float_as_uint(acc[nb][r]);
                u32 kv = (u & 0x80000000u) ? ~u : (u | 0x80000000u);  // order-preserving
                atomicMax(&key[b * EMBD + n], kv);
            }
        }
    }
}

// ---------------- K5: inverse transform + decoder bias -----------------------
__global__ void k_final(const u32* __restrict__ key, const float* __restrict__ db,
                        float* __restrict__ out) {
    int i = blockIdx.x * 256 + threadIdx.x;
    if (i < BATCH * EMBD) {
        u32 k = key[i];
        u32 u = (k & 0x80000000u) ? (k & 0x7fffffffu) : ~k;
        out[i] = __uint_as_float(u) + db[i % EMBD];
    }
}

extern "C" void kernel_launch(void* const* d_in, const int* in_sizes, int n_in,
                              void* d_out, int out_size, void* d_ws, size_t ws_size,
                              hipStream_t stream) {
    const int*   x   = (const int*)d_in[0];
    const float* emb = (const float*)d_in[1];
    const float* wih = (const float*)d_in[2];
    const float* whh = (const float*)d_in[3];
    const float* bih = (const float*)d_in[4];
    const float* bhh = (const float*)d_in[5];
    const float* gam = (const float*)d_in[6];
    const float* bet = (const float*)d_in[7];
    const float* dw  = (const float*)d_in[8];
    const float* db  = (const float*)d_in[9];
    const float* msk = (const float*)d_in[10];

    char* ws = (char*)d_ws;
    unsigned short* A   = (unsigned short*)(ws + A_OFF);
    unsigned short* hd  = (unsigned short*)(ws + HD_OFF);
    unsigned short* hx  = (unsigned short*)(ws + HB_OFF);
    u32*            flg = (u32*)(ws + FLG_OFF);
    u32*            key = (u32*)(ws + KEY_OFF);
    unsigned short* dwb = (unsigned short*)(ws + DW_OFF);

    hipMemsetAsync(ws + FLG_OFF, 0, MS_SPAN, stream);       // flags + keys
    k_dw     <<<224,  256, 0, stream>>>(dw, dwb);
    k_hxinit <<<384,  256, 0, stream>>>(hx);
    k_embed  <<<8192, 256, 0, stream>>>(x, emb, A);
    k_lstm   <<<NWG,  512, 0, stream>>>(wih, whh, bih, bhh, gam, bet, msk, A, hx, hd, flg);
    k_decode <<<TSEQ, 256, 0, stream>>>(hd, dwb, key);
    k_final  <<<25,   256, 0, stream>>>(key, db, (float*)d_out);
}